// Round 3
// baseline (727.542 us; speedup 1.0000x reference)
//
#include <hip/hip_runtime.h>
#include <math.h>

// Problem constants
#define N_CELLS 50000
#define C_CLS   30
#define G_GENES 1000
#define E_EDGES 800000
#define KPAD    1024

typedef __attribute__((ext_vector_type(8))) short bf16x8;
typedef __attribute__((ext_vector_type(4))) float f32x4;

// fp32 -> bf16 (RNE), raw ushort payload
__device__ __forceinline__ unsigned f2bf_u(float f) {
    unsigned u = __float_as_uint(f);
    return (u + 0x7fffu + ((u >> 16) & 1u)) >> 16;
}
__device__ __forceinline__ unsigned pack2(float lo, float hi) {
    return f2bf_u(lo) | (f2bf_u(hi) << 16);
}

__device__ __forceinline__ float lrelu02(float v) { return v > 0.f ? v : 0.2f * v; }

// ---------------------------------------------------------------------------
// K0: pack CoefB bf16 [80][1024] + Dvec[30] + zero denom/out accumulators.
//   rows 0..29  : 1/Var    (X^2 GEMM)        rows 30,31: 0
//   rows 32..61 : Mu/Var   rows 62..69: Wl   rows 70..77: Wr   78,79: 0
// ---------------------------------------------------------------------------
__global__ void prep_kernel(const float* __restrict__ Mu, const float* __restrict__ Var,
                            const float* __restrict__ Wl, const float* __restrict__ Wr,
                            unsigned short* __restrict__ CoefB, float* __restrict__ Dvec,
                            float* __restrict__ denom, float* __restrict__ out) {
    const int r = blockIdx.x;
    const int t = threadIdx.x;
    __shared__ float red[256];
    float dacc = 0.f;
    for (int g = t; g < KPAD; g += 256) {
        float v = 0.f;
        if (g < G_GENES) {
            if (r < 30) {
                float iv = 1.0f / Var[r * G_GENES + g];
                float mu = Mu[r * G_GENES + g];
                v = iv;
                dacc += mu * mu * iv;
            } else if (r >= 32) {
                int i = r - 32;
                if (i < 30)      v = Mu[i * G_GENES + g] / Var[i * G_GENES + g];
                else if (i < 38) v = Wl[(i - 30) * G_GENES + g];
                else if (i < 46) v = Wr[(i - 38) * G_GENES + g];
            }
        }
        CoefB[r * KPAD + g] = (unsigned short)f2bf_u(v);
    }
    // zero denom (grid-stride over all 80*256 threads) and out[0..1]
    for (int i = blockIdx.x * 256 + t; i < N_CELLS; i += 80 * 256) denom[i] = 0.f;
    if (r == 31 && t < 2) out[t] = 0.f;

    if (r < 30) {
        red[t] = dacc;
        __syncthreads();
        for (int s = 128; s > 0; s >>= 1) {
            if (t < s) red[t] += red[t + s];
            __syncthreads();
        }
        if (t == 0) Dvec[r] = red[0];
    }
}

// ---------------------------------------------------------------------------
// K1: MFMA row kernel, LDS-free K-loop. 64 rows/block, 4 waves.
// Wave w owns rows w*16..w*16+15. A-frags loaded straight from X (2 x float4
// per lane per 32-k step), packed to bf16 (and squared) in registers.
// B-frags read directly from L1/L2-hot CoefB. No barriers in the K-loop.
// ---------------------------------------------------------------------------
__global__ __launch_bounds__(256) void main_rows_kernel(
    const float* __restrict__ X, const float* __restrict__ W,
    const float* __restrict__ S, const float* __restrict__ bl,
    const float* __restrict__ br, const unsigned short* __restrict__ CoefB,
    const float* __restrict__ Dvec,
    float* __restrict__ out,          // [0]=ll, [1]=ce, [2..] = P row-major
    float* __restrict__ logP, float* __restrict__ xl, float* __restrict__ xr)
{
    __shared__ float ob[64 * 81];     // 20.7 KB, epilogue exchange only

    const int t    = threadIdx.x;
    const int w    = t >> 6;
    const int l    = t & 63;
    const int l15  = l & 15;
    const int quad = l >> 4;
    const int rowbase = blockIdx.x * 64;
    const int myrow = rowbase + w * 16 + l15;
    const bool rowok = (myrow < N_CELLS);
    const float* __restrict__ xrow = X + (size_t)myrow * G_GENES;

    f32x4 acc[5];
#pragma unroll
    for (int i = 0; i < 5; i++) acc[i] = (f32x4){0.f, 0.f, 0.f, 0.f};

#pragma unroll 2
    for (int kt = 0; kt < KPAD; kt += 32) {
        const int k0 = kt + quad * 8;
        float4 f0 = make_float4(0.f, 0.f, 0.f, 0.f);
        float4 f1 = make_float4(0.f, 0.f, 0.f, 0.f);
        if (rowok && k0 < G_GENES) {       // k0 % 8 == 0, so k0+7 <= 999 here
            f0 = *(const float4*)&xrow[k0];
            f1 = *(const float4*)&xrow[k0 + 4];
        }
        union { unsigned u[4]; bf16x8 v; } ua, u2;
        ua.u[0] = pack2(f0.x, f0.y);
        ua.u[1] = pack2(f0.z, f0.w);
        ua.u[2] = pack2(f1.x, f1.y);
        ua.u[3] = pack2(f1.z, f1.w);
        u2.u[0] = pack2(f0.x * f0.x, f0.y * f0.y);
        u2.u[1] = pack2(f0.z * f0.z, f0.w * f0.w);
        u2.u[2] = pack2(f1.x * f1.x, f1.y * f1.y);
        u2.u[3] = pack2(f1.z * f1.z, f1.w * f1.w);
#pragma unroll
        for (int nt = 0; nt < 5; nt++) {
            bf16x8 b = *(const bf16x8*)&CoefB[(nt * 16 + l15) * KPAD + k0];
            acc[nt] = __builtin_amdgcn_mfma_f32_16x16x32_bf16(
                nt < 2 ? u2.v : ua.v, b, acc[nt], 0, 0, 0);
        }
    }

    // dump accumulators: C/D layout col=lane&15, row=quad*4+reg
#pragma unroll
    for (int nt = 0; nt < 5; nt++)
#pragma unroll
        for (int r = 0; r < 4; r++)
            ob[(w * 16 + quad * 4 + r) * 81 + nt * 16 + l15] = acc[nt][r];
    __syncthreads();

    // epilogue: wave 0, one lane per row
    if (t < 64) {
        float llrow = 0.f;
        int n = rowbase + t;
        if (n < N_CELLS) {
            float wv[30];
            const float2* wrow = (const float2*)&W[(size_t)n * 30];
            float m = -1e30f;
#pragma unroll
            for (int c = 0; c < 15; c++) {
                float2 f = wrow[c];
                wv[2 * c] = f.x; wv[2 * c + 1] = f.y;
                m = fmaxf(m, fmaxf(f.x, f.y));
            }
            float s = 0.f;
#pragma unroll
            for (int c = 0; c < 30; c++) { wv[c] = expf(wv[c] - m); s += wv[c]; }
            float inv = 1.0f / s;
            float Sn  = S[n];
            float Sn2 = Sn * Sn;
#pragma unroll
            for (int c = 0; c < 30; c++) {
                float p = wv[c] * inv;
                out[2 + (size_t)n * 30 + c] = p;
                logP[(size_t)n * 30 + c] = logf(p + 1e-8f);
                float Av = ob[t * 81 + c];
                float Bv = ob[t * 81 + 32 + c];
                float F  = -0.5f * (Av - 2.0f * Sn * Bv + Sn2 * Dvec[c]);
                llrow += p * F;
            }
#pragma unroll
            for (int o = 0; o < 8; o++) {
                xl[(size_t)n * 8 + o] = ob[t * 81 + 62 + o] + bl[o];
                xr[(size_t)n * 8 + o] = ob[t * 81 + 70 + o] + br[o];
            }
        }
        for (int off = 32; off > 0; off >>= 1) llrow += __shfl_down(llrow, off, 64);
        if (t == 0) atomicAdd(&out[0], llrow * (1.0f / N_CELLS));
    }
}

// ---------------------------------------------------------------------------
// K2: edge pass A — p=exp(e) (no max-subtraction: |e| ~ O(10)), denom atomics
// ---------------------------------------------------------------------------
__global__ void edge_passA(const int* __restrict__ ei, const float* __restrict__ xl,
                           const float* __restrict__ xr, const float* __restrict__ att,
                           float* __restrict__ evals, float* __restrict__ denom) {
    int e = blockIdx.x * 256 + threadIdx.x;
    if (e >= E_EDGES) return;
    int src = ei[e];
    int dst = ei[E_EDGES + e];
    const float4* lp = (const float4*)&xl[(size_t)src * 8];
    const float4* rp = (const float4*)&xr[(size_t)dst * 8];
    float4 l0 = lp[0], l1 = lp[1];
    float4 r0 = rp[0], r1 = rp[1];
    float ev = 0.f;
    ev += lrelu02(l0.x + r0.x) * att[0];
    ev += lrelu02(l0.y + r0.y) * att[1];
    ev += lrelu02(l0.z + r0.z) * att[2];
    ev += lrelu02(l0.w + r0.w) * att[3];
    ev += lrelu02(l1.x + r1.x) * att[4];
    ev += lrelu02(l1.y + r1.y) * att[5];
    ev += lrelu02(l1.z + r1.z) * att[6];
    ev += lrelu02(l1.w + r1.w) * att[7];
    float p = __expf(ev);
    evals[e] = p;
    atomicAdd(&denom[dst], p);
}

// ---------------------------------------------------------------------------
// K3: edge pass B — 8 lanes per edge, coalesced float2 row segments,
// full-wave butterfly reduction, one atomic per block.
// ---------------------------------------------------------------------------
__global__ __launch_bounds__(256) void edge_passB(
    const int* __restrict__ ei, const float* __restrict__ evals,
    const float* __restrict__ denom, const float* __restrict__ P,
    const float* __restrict__ logP, float* __restrict__ out) {
    const int t    = threadIdx.x;
    const int lane = t & 63;
    const int sub  = lane >> 3;             // edge slot within wave (0..7)
    const int cl   = t & 7;                 // class chunk (4 classes each)
    const long wid = (long)blockIdx.x * 4 + (t >> 6);
    const long e   = wid * 8 + sub;
    float contrib = 0.f;
    if (e < E_EDGES) {
        int src = ei[e];
        int dst = ei[E_EDGES + e];
        float alpha = evals[e] / (denom[dst] + 1e-16f);
        int c0 = cl * 4;
        const float* ps = &P[(size_t)src * 30 + c0];
        const float* ld = &logP[(size_t)dst * 30 + c0];
        float dot;
        if (cl < 7) {
            float2 p0 = *(const float2*)ps;
            float2 p1 = *(const float2*)(ps + 2);
            float2 q0 = *(const float2*)ld;
            float2 q1 = *(const float2*)(ld + 2);
            dot = p0.x * q0.x + p0.y * q0.y + p1.x * q1.x + p1.y * q1.y;
        } else {
            float2 p0 = *(const float2*)ps;
            float2 q0 = *(const float2*)ld;
            dot = p0.x * q0.x + p0.y * q0.y;
        }
        contrib = -alpha * dot;
    }
    // full 64-lane butterfly: sums all per-lane partials = 8 edges' totals
    for (int m = 1; m < 64; m <<= 1) contrib += __shfl_xor(contrib, m, 64);
    __shared__ float wsum[4];
    if (lane == 0) wsum[t >> 6] = contrib;
    __syncthreads();
    if (t == 0)
        atomicAdd(&out[1], (wsum[0] + wsum[1] + wsum[2] + wsum[3]) * (1.0f / N_CELLS));
}

// ---------------------------------------------------------------------------
// launch
// ---------------------------------------------------------------------------
extern "C" void kernel_launch(void* const* d_in, const int* in_sizes, int n_in,
                              void* d_out, int out_size, void* d_ws, size_t ws_size,
                              hipStream_t stream) {
    const float* X   = (const float*)d_in[0];
    const float* Mu  = (const float*)d_in[1];
    const float* Var = (const float*)d_in[2];
    const int*   ei  = (const int*)d_in[3];
    const float* W   = (const float*)d_in[4];
    const float* S   = (const float*)d_in[5];
    const float* Wl  = (const float*)d_in[6];
    const float* bl  = (const float*)d_in[7];
    const float* Wr  = (const float*)d_in[8];
    const float* br  = (const float*)d_in[9];
    const float* att = (const float*)d_in[10];

    float* out = (float*)d_out;

    // ws layout (floats)
    float* wsf   = (float*)d_ws;
    unsigned short* CoefB = (unsigned short*)wsf;   // 80*1024 bf16
    float* Dvec  = wsf + 40960;                     // 32
    float* logP  = wsf + 40992;                     // N*30
    float* xl    = wsf + 1540992;                   // N*8
    float* xr    = wsf + 1940992;                   // N*8
    float* evals = wsf + 2340992;                   // E
    float* denom = wsf + 3140992;                   // N

    prep_kernel<<<80, 256, 0, stream>>>(Mu, Var, Wl, Wr, CoefB, Dvec, denom, out);
    main_rows_kernel<<<(N_CELLS + 63) / 64, 256, 0, stream>>>(
        X, W, S, bl, br, CoefB, Dvec, out, logP, xl, xr);
    edge_passA<<<(E_EDGES + 255) / 256, 256, 0, stream>>>(ei, xl, xr, att, evals, denom);
    edge_passB<<<(E_EDGES * 8 + 255) / 256, 256, 0, stream>>>(ei, evals, denom,
                                                              out + 2, logP, out);
}

// Round 5
// 456.607 us; speedup vs baseline: 1.5934x; 1.5934x over previous
//
#include <hip/hip_runtime.h>
#include <math.h>

// Problem constants
#define N_CELLS 50000
#define C_CLS   30
#define G_GENES 1000
#define E_EDGES 800000
#define KPAD    1024

typedef __attribute__((ext_vector_type(8))) short bf16x8;
typedef __attribute__((ext_vector_type(4))) float f32x4;

// fp32 -> bf16 (RNE), raw ushort payload
__device__ __forceinline__ unsigned f2bf_u(float f) {
    unsigned u = __float_as_uint(f);
    return (u + 0x7fffu + ((u >> 16) & 1u)) >> 16;
}
__device__ __forceinline__ unsigned pack2(float lo, float hi) {
    return f2bf_u(lo) | (f2bf_u(hi) << 16);
}

__device__ __forceinline__ float lrelu02(float v) { return v > 0.f ? v : 0.2f * v; }

// dot of 8 bf16 pairs packed in int4s
__device__ __forceinline__ float dp4(int4 a, int4 b) {
    const unsigned* ua = (const unsigned*)&a;
    const unsigned* ub = (const unsigned*)&b;
    float s = 0.f;
#pragma unroll
    for (int i = 0; i < 4; i++) {
        float al = __uint_as_float(ua[i] << 16);
        float ah = __uint_as_float(ua[i] & 0xffff0000u);
        float bl = __uint_as_float(ub[i] << 16);
        float bh = __uint_as_float(ub[i] & 0xffff0000u);
        s += al * bl + ah * bh;
    }
    return s;
}

// ---------------------------------------------------------------------------
// K0: pack CoefB bf16 [80][1024] + Dvec[30]; zero denom + out[0..1].
//   rows 0..29: 1/Var  30,31: 0  32..61: Mu/Var  62..69: Wl  70..77: Wr  78,79: 0
// ---------------------------------------------------------------------------
__global__ void prep_kernel(const float* __restrict__ Mu, const float* __restrict__ Var,
                            const float* __restrict__ Wl, const float* __restrict__ Wr,
                            unsigned short* __restrict__ CoefB, float* __restrict__ Dvec,
                            float* __restrict__ denom, float* __restrict__ out) {
    const int r = blockIdx.x;
    const int t = threadIdx.x;
    __shared__ float red[256];
    float dacc = 0.f;
    for (int g = t; g < KPAD; g += 256) {
        float v = 0.f;
        if (g < G_GENES) {
            if (r < 30) {
                float iv = 1.0f / Var[r * G_GENES + g];
                float mu = Mu[r * G_GENES + g];
                v = iv;
                dacc += mu * mu * iv;
            } else if (r >= 32) {
                int i = r - 32;
                if (i < 30)      v = Mu[i * G_GENES + g] / Var[i * G_GENES + g];
                else if (i < 38) v = Wl[(i - 30) * G_GENES + g];
                else if (i < 46) v = Wr[(i - 38) * G_GENES + g];
            }
        }
        CoefB[r * KPAD + g] = (unsigned short)f2bf_u(v);
    }
    for (int i = blockIdx.x * 256 + t; i < N_CELLS; i += 80 * 256) denom[i] = 0.f;
    if (r == 31 && t < 2) out[t] = 0.f;

    if (r < 30) {
        red[t] = dacc;
        __syncthreads();
        for (int s = 128; s > 0; s >>= 1) {
            if (t < s) red[t] += red[t + s];
            __syncthreads();
        }
        if (t == 0) Dvec[r] = red[0];
    }
}

// ---------------------------------------------------------------------------
// K1: MFMA row kernel (hybrid). 64 rows/block, 4 waves, wave w owns rows
// w*16..w*16+15. Ct staged in LDS (cross-wave reuse); X loaded directly
// (no reuse), packed to bf16 + bf16^2 in registers. Per-wave shfl epilogue.
// ---------------------------------------------------------------------------
__global__ __launch_bounds__(256, 4) void main_rows_kernel(
    const float* __restrict__ X, const float* __restrict__ W,
    const float* __restrict__ S, const float* __restrict__ bl,
    const float* __restrict__ br, const unsigned short* __restrict__ CoefB,
    const float* __restrict__ Dvec,
    float* __restrict__ out,          // [0]=ll, [1]=ce, [2..] = P row-major
    unsigned short* __restrict__ Pb, unsigned short* __restrict__ Lb,
    float* __restrict__ xl, float* __restrict__ xr)
{
    __shared__ __align__(16) unsigned short Ct[80 * 72];   // 11.25 KB

    const int t    = threadIdx.x;
    const int w    = t >> 6;
    const int l    = t & 63;
    const int l15  = l & 15;
    const int quad = l >> 4;
    const int wavebase = blockIdx.x * 64 + w * 16;
    const bool valid = (wavebase < N_CELLS);     // uniform per wave
    const float* __restrict__ xrow = X + (size_t)(wavebase + l15) * G_GENES;

    f32x4 acc[5];
#pragma unroll
    for (int i = 0; i < 5; i++) acc[i] = (f32x4){0.f, 0.f, 0.f, 0.f};

    for (int kt = 0; kt < KPAD; kt += 64) {
        __syncthreads();
        for (int u = t; u < 640; u += 256) {
            int row = u >> 3;
            int kk  = (u & 7) * 8;
            *(int4*)&Ct[row * 72 + kk] = *(const int4*)&CoefB[row * KPAD + kt + kk];
        }
        __syncthreads();
#pragma unroll
        for (int ks = 0; ks < 2; ks++) {
            const int k0 = kt + ks * 32 + quad * 8;
            float4 f0 = make_float4(0.f, 0.f, 0.f, 0.f);
            float4 f1 = make_float4(0.f, 0.f, 0.f, 0.f);
            if (valid && k0 < G_GENES) {      // k0 % 8 == 0 -> k0+7 <= 999
                f0 = *(const float4*)&xrow[k0];
                f1 = *(const float4*)&xrow[k0 + 4];
            }
            union { unsigned u[4]; bf16x8 v; } ua, u2;
            ua.u[0] = pack2(f0.x, f0.y);
            ua.u[1] = pack2(f0.z, f0.w);
            ua.u[2] = pack2(f1.x, f1.y);
            ua.u[3] = pack2(f1.z, f1.w);
            u2.u[0] = pack2(f0.x * f0.x, f0.y * f0.y);
            u2.u[1] = pack2(f0.z * f0.z, f0.w * f0.w);
            u2.u[2] = pack2(f1.x * f1.x, f1.y * f1.y);
            u2.u[3] = pack2(f1.z * f1.z, f1.w * f1.w);
#pragma unroll
            for (int nt = 0; nt < 5; nt++) {
                bf16x8 b = *(const bf16x8*)&Ct[(nt * 16 + l15) * 72 + ks * 32 + quad * 8];
                acc[nt] = __builtin_amdgcn_mfma_f32_16x16x32_bf16(
                    nt < 2 ? u2.v : ua.v, b, acc[nt], 0, 0, 0);
            }
        }
    }

    if (!valid) return;   // no barriers below

    // Epilogue, per wave. acc[nt][reg]: packed col = nt*16+l15, row = quad*4+reg.
    // packed cols: 0..29 A | 32..61 B | 62..69 xl | 70..77 xr
    const int rbase = wavebase + quad * 4;
    const bool c2ok = (l15 < 14);
    const float d0 = Dvec[l15];
    const float d1 = c2ok ? Dvec[16 + l15] : 0.f;
    float llacc = 0.f;
#pragma unroll
    for (int r = 0; r < 4; r++) {
        const int row = rbase + r;
        float w0 = W[(size_t)row * 30 + l15];
        float w1 = c2ok ? W[(size_t)row * 30 + 16 + l15] : -1e30f;
        float m = fmaxf(w0, w1);
#pragma unroll
        for (int mm = 1; mm < 16; mm <<= 1) m = fmaxf(m, __shfl_xor(m, mm, 64));
        float e0 = __expf(w0 - m);
        float e1 = c2ok ? __expf(w1 - m) : 0.f;
        float s = e0 + e1;
#pragma unroll
        for (int mm = 1; mm < 16; mm <<= 1) s += __shfl_xor(s, mm, 64);
        float inv = 1.0f / s;
        float p0 = e0 * inv, p1 = e1 * inv;
        float Sn = S[row], Sn2 = Sn * Sn;
        float F0 = -0.5f * (acc[0][r] - 2.0f * Sn * acc[2][r] + Sn2 * d0);
        float F1 = -0.5f * (acc[1][r] - 2.0f * Sn * acc[3][r] + Sn2 * d1);
        float lp = p0 * F0 + (c2ok ? p1 * F1 : 0.f);
#pragma unroll
        for (int mm = 1; mm < 16; mm <<= 1) lp += __shfl_xor(lp, mm, 64);
        llacc += lp;

        out[2 + (size_t)row * 30 + l15] = p0;
        float lg0 = __logf(p0 + 1e-8f);
        Pb[(size_t)row * 32 + l15] = (unsigned short)f2bf_u(p0);
        Lb[(size_t)row * 32 + l15] = (unsigned short)f2bf_u(lg0);
        if (c2ok) {
            out[2 + (size_t)row * 30 + 16 + l15] = p1;
            float lg1 = __logf(p1 + 1e-8f);
            Pb[(size_t)row * 32 + 16 + l15] = (unsigned short)f2bf_u(p1);
            Lb[(size_t)row * 32 + 16 + l15] = (unsigned short)f2bf_u(lg1);
        } else {
            Pb[(size_t)row * 32 + 16 + l15] = 0;
            Lb[(size_t)row * 32 + 16 + l15] = 0;
        }
        // xl: packed cols 62,63 (acc[3], l15=14,15) and 64..69 (acc[4], l15=0..5)
        if (l15 >= 14)                xl[(size_t)row * 8 + (l15 - 14)] = acc[3][r] + bl[l15 - 14];
        else if (l15 < 6)             xl[(size_t)row * 8 + (l15 + 2)]  = acc[4][r] + bl[l15 + 2];
        if (l15 >= 6 && l15 < 14)     xr[(size_t)row * 8 + (l15 - 6)]  = acc[4][r] + br[l15 - 6];
    }
    llacc += __shfl_xor(llacc, 16, 64);
    llacc += __shfl_xor(llacc, 32, 64);
    if (l == 0) atomicAdd(&out[0], llacc * (1.0f / N_CELLS));
}

// ---------------------------------------------------------------------------
// K2: edge pass A — p=exp(e) (no max-subtraction: |e| ~ O(10)), denom atomics
// ---------------------------------------------------------------------------
__global__ void edge_passA(const int* __restrict__ ei, const float* __restrict__ xl,
                           const float* __restrict__ xr, const float* __restrict__ att,
                           float* __restrict__ evals, float* __restrict__ denom) {
    int e = blockIdx.x * 256 + threadIdx.x;
    if (e >= E_EDGES) return;
    int src = ei[e];
    int dst = ei[E_EDGES + e];
    const float4* lp = (const float4*)&xl[(size_t)src * 8];
    const float4* rp = (const float4*)&xr[(size_t)dst * 8];
    float4 l0 = lp[0], l1 = lp[1];
    float4 r0 = rp[0], r1 = rp[1];
    float ev = 0.f;
    ev += lrelu02(l0.x + r0.x) * att[0];
    ev += lrelu02(l0.y + r0.y) * att[1];
    ev += lrelu02(l0.z + r0.z) * att[2];
    ev += lrelu02(l0.w + r0.w) * att[3];
    ev += lrelu02(l1.x + r1.x) * att[4];
    ev += lrelu02(l1.y + r1.y) * att[5];
    ev += lrelu02(l1.z + r1.z) * att[6];
    ev += lrelu02(l1.w + r1.w) * att[7];
    float p = __expf(ev);
    evals[e] = p;
    atomicAdd(&denom[dst], p);
}

// ---------------------------------------------------------------------------
// K3: edge pass B — 1 thread/edge, bf16 64-B rows (exactly 2 cache lines/edge)
// ---------------------------------------------------------------------------
__global__ __launch_bounds__(256) void edge_passB(
    const int* __restrict__ ei, const float* __restrict__ evals,
    const float* __restrict__ denom, const unsigned short* __restrict__ Pb,
    const unsigned short* __restrict__ Lb, float* __restrict__ out) {
    const int t = threadIdx.x;
    const int e = blockIdx.x * 256 + t;     // E = 3125*256 exactly
    int src = ei[e];
    int dst = ei[E_EDGES + e];
    float alpha = evals[e] / (denom[dst] + 1e-16f);
    const int4* ps = (const int4*)&Pb[(size_t)src * 32];
    const int4* ld = (const int4*)&Lb[(size_t)dst * 32];
    int4 a0 = ps[0], a1 = ps[1], a2 = ps[2], a3 = ps[3];
    int4 b0 = ld[0], b1 = ld[1], b2 = ld[2], b3 = ld[3];
    float dot = dp4(a0, b0) + dp4(a1, b1) + dp4(a2, b2) + dp4(a3, b3);
    float contrib = -alpha * dot;

    for (int m = 1; m < 64; m <<= 1) contrib += __shfl_xor(contrib, m, 64);
    __shared__ float wsum[4];
    if ((t & 63) == 0) wsum[t >> 6] = contrib;
    __syncthreads();
    if (t == 0)
        atomicAdd(&out[1], (wsum[0] + wsum[1] + wsum[2] + wsum[3]) * (1.0f / N_CELLS));
}

// ---------------------------------------------------------------------------
// launch
// ---------------------------------------------------------------------------
extern "C" void kernel_launch(void* const* d_in, const int* in_sizes, int n_in,
                              void* d_out, int out_size, void* d_ws, size_t ws_size,
                              hipStream_t stream) {
    const float* X   = (const float*)d_in[0];
    const float* Mu  = (const float*)d_in[1];
    const float* Var = (const float*)d_in[2];
    const int*   ei  = (const int*)d_in[3];
    const float* W   = (const float*)d_in[4];
    const float* S   = (const float*)d_in[5];
    const float* Wl  = (const float*)d_in[6];
    const float* bl  = (const float*)d_in[7];
    const float* Wr  = (const float*)d_in[8];
    const float* br  = (const float*)d_in[9];
    const float* att = (const float*)d_in[10];

    float* out = (float*)d_out;

    // ws layout (float offsets). Pb/Lb are N*32 ushorts = 800000 floats EACH.
    float* wsf = (float*)d_ws;
    unsigned short* CoefB = (unsigned short*)wsf;            // [0, 40960) fl
    float* Dvec  = wsf + 40960;                              // 32
    unsigned short* Pb = (unsigned short*)(wsf + 40992);     // [40992, 840992)
    unsigned short* Lb = (unsigned short*)(wsf + 840992);    // [840992, 1640992)
    float* xl    = wsf + 1640992;                            // N*8 = 400000
    float* xr    = wsf + 2040992;                            // N*8
    float* evals = wsf + 2440992;                            // E = 800000
    float* denom = wsf + 3240992;                            // N
    // total: 3290992 floats ~= 13.2 MB

    prep_kernel<<<80, 256, 0, stream>>>(Mu, Var, Wl, Wr, CoefB, Dvec, denom, out);
    main_rows_kernel<<<(N_CELLS + 63) / 64, 256, 0, stream>>>(
        X, W, S, bl, br, CoefB, Dvec, out, Pb, Lb, xl, xr);
    edge_passA<<<(E_EDGES + 255) / 256, 256, 0, stream>>>(ei, xl, xr, att, evals, denom);
    edge_passB<<<E_EDGES / 256, 256, 0, stream>>>(ei, evals, denom, Pb, Lb, out);
}

// Round 6
// 452.091 us; speedup vs baseline: 1.6093x; 1.0100x over previous
//
#include <hip/hip_runtime.h>
#include <math.h>

// Problem constants
#define N_CELLS 50000
#define C_CLS   30
#define G_GENES 1000
#define E_EDGES 800000
#define KPAD    1024
#define NREP    4

typedef __attribute__((ext_vector_type(8))) short bf16x8;
typedef __attribute__((ext_vector_type(4))) float f32x4;

// fp32 -> bf16 (RNE), raw ushort payload
__device__ __forceinline__ unsigned f2bf_u(float f) {
    unsigned u = __float_as_uint(f);
    return (u + 0x7fffu + ((u >> 16) & 1u)) >> 16;
}
__device__ __forceinline__ unsigned pack2(float lo, float hi) {
    return f2bf_u(lo) | (f2bf_u(hi) << 16);
}
__device__ __forceinline__ float bf2f(unsigned short u) {
    return __uint_as_float(((unsigned)u) << 16);
}

__device__ __forceinline__ float lrelu02(float v) { return v > 0.f ? v : 0.2f * v; }

// dot of 8 bf16 pairs packed in int4s
__device__ __forceinline__ float dp4(int4 a, int4 b) {
    const unsigned* ua = (const unsigned*)&a;
    const unsigned* ub = (const unsigned*)&b;
    float s = 0.f;
#pragma unroll
    for (int i = 0; i < 4; i++) {
        float al = __uint_as_float(ua[i] << 16);
        float ah = __uint_as_float(ua[i] & 0xffff0000u);
        float bl = __uint_as_float(ub[i] << 16);
        float bh = __uint_as_float(ub[i] & 0xffff0000u);
        s += al * bl + ah * bh;
    }
    return s;
}

// ---------------------------------------------------------------------------
// K0: pack CoefB bf16 [80][1024] + Dvec[30]; zero denom replicas + out[0..1].
// ---------------------------------------------------------------------------
__global__ void prep_kernel(const float* __restrict__ Mu, const float* __restrict__ Var,
                            const float* __restrict__ Wl, const float* __restrict__ Wr,
                            unsigned short* __restrict__ CoefB, float* __restrict__ Dvec,
                            float* __restrict__ denom4, float* __restrict__ out) {
    const int r = blockIdx.x;
    const int t = threadIdx.x;
    __shared__ float red[256];
    float dacc = 0.f;
    for (int g = t; g < KPAD; g += 256) {
        float v = 0.f;
        if (g < G_GENES) {
            if (r < 30) {
                float iv = 1.0f / Var[r * G_GENES + g];
                float mu = Mu[r * G_GENES + g];
                v = iv;
                dacc += mu * mu * iv;
            } else if (r >= 32) {
                int i = r - 32;
                if (i < 30)      v = Mu[i * G_GENES + g] / Var[i * G_GENES + g];
                else if (i < 38) v = Wl[(i - 30) * G_GENES + g];
                else if (i < 46) v = Wr[(i - 38) * G_GENES + g];
            }
        }
        CoefB[r * KPAD + g] = (unsigned short)f2bf_u(v);
    }
    for (int i = blockIdx.x * 256 + t; i < N_CELLS * NREP; i += 80 * 256) denom4[i] = 0.f;
    if (r == 31 && t < 2) out[t] = 0.f;

    if (r < 30) {
        red[t] = dacc;
        __syncthreads();
        for (int s = 128; s > 0; s >>= 1) {
            if (t < s) red[t] += red[t + s];
            __syncthreads();
        }
        if (t == 0) Dvec[r] = red[0];
    }
}

// ---------------------------------------------------------------------------
// K1: MFMA row kernel, software-pipelined X prefetch.
// 64 rows/block, 4 waves; wave w owns rows w*16..w*16+15.
// Ct staged in LDS (cross-wave reuse); X prefetched into registers one
// K-tile ahead so the global-load latency is hidden under pack+MFMA.
// ---------------------------------------------------------------------------
__global__ __launch_bounds__(256, 4) void main_rows_kernel(
    const float* __restrict__ X, const float* __restrict__ W,
    const float* __restrict__ S, const float* __restrict__ bl,
    const float* __restrict__ br, const unsigned short* __restrict__ CoefB,
    const float* __restrict__ Dvec,
    float* __restrict__ out,          // [0]=ll, [1]=ce, [2..] = P row-major
    unsigned short* __restrict__ Pb, unsigned short* __restrict__ Lb,
    float* __restrict__ xl, float* __restrict__ xr)
{
    __shared__ __align__(16) unsigned short Ct[80 * 72];   // 11.25 KB

    const int t    = threadIdx.x;
    const int w    = t >> 6;
    const int l    = t & 63;
    const int l15  = l & 15;
    const int quad = l >> 4;
    const int k0q  = quad * 8;
    const int wavebase = blockIdx.x * 64 + w * 16;
    const bool valid = (wavebase < N_CELLS);     // uniform per wave (N%16==0)
    const float* __restrict__ xrow = X + (size_t)(wavebase + l15) * G_GENES;

    f32x4 acc[5];
#pragma unroll
    for (int i = 0; i < 5; i++) acc[i] = (f32x4){0.f, 0.f, 0.f, 0.f};

    // prefetch K-tile 0: ks=0 pair (always in-bounds: k <= 984+7), ks=1 pair
    float4 c0a = make_float4(0,0,0,0), c0b = c0a, c1a = c0a, c1b = c0a;
    if (valid) {
        c0a = *(const float4*)&xrow[k0q];
        c0b = *(const float4*)&xrow[k0q + 4];
        c1a = *(const float4*)&xrow[32 + k0q];
        c1b = *(const float4*)&xrow[32 + k0q + 4];
    }

    for (int kt = 0; kt < KPAD; kt += 64) {
        __syncthreads();                       // prev iter's Ct reads done
        for (int u = t; u < 640; u += 256) {
            int row = u >> 3;
            int kk  = (u & 7) * 8;
            *(int4*)&Ct[row * 72 + kk] = *(const int4*)&CoefB[row * KPAD + kt + kk];
        }
        __syncthreads();                       // Ct(kt) ready

        // issue next tile's X loads (consumed next iteration)
        float4 n0a = make_float4(0,0,0,0), n0b = n0a, n1a = n0a, n1b = n0a;
        const int ktn = kt + 64;
        if (valid && ktn < KPAD) {
            const int ka = ktn + k0q;          // ka+7 <= 991 always
            n0a = *(const float4*)&xrow[ka];
            n0b = *(const float4*)&xrow[ka + 4];
            const int kb = ktn + 32 + k0q;
            if (kb < G_GENES) {                // kb can reach 1016
                n1a = *(const float4*)&xrow[kb];
                n1b = *(const float4*)&xrow[kb + 4];
            }
        }

        // ---- pack + MFMA on current regs ----
        union { unsigned u[4]; bf16x8 v; } ua, u2;
        // ks = 0
        ua.u[0] = pack2(c0a.x, c0a.y); ua.u[1] = pack2(c0a.z, c0a.w);
        ua.u[2] = pack2(c0b.x, c0b.y); ua.u[3] = pack2(c0b.z, c0b.w);
        u2.u[0] = pack2(c0a.x * c0a.x, c0a.y * c0a.y);
        u2.u[1] = pack2(c0a.z * c0a.z, c0a.w * c0a.w);
        u2.u[2] = pack2(c0b.x * c0b.x, c0b.y * c0b.y);
        u2.u[3] = pack2(c0b.z * c0b.z, c0b.w * c0b.w);
#pragma unroll
        for (int nt = 0; nt < 5; nt++) {
            bf16x8 b = *(const bf16x8*)&Ct[(nt * 16 + l15) * 72 + k0q];
            acc[nt] = __builtin_amdgcn_mfma_f32_16x16x32_bf16(
                nt < 2 ? u2.v : ua.v, b, acc[nt], 0, 0, 0);
        }
        // ks = 1
        ua.u[0] = pack2(c1a.x, c1a.y); ua.u[1] = pack2(c1a.z, c1a.w);
        ua.u[2] = pack2(c1b.x, c1b.y); ua.u[3] = pack2(c1b.z, c1b.w);
        u2.u[0] = pack2(c1a.x * c1a.x, c1a.y * c1a.y);
        u2.u[1] = pack2(c1a.z * c1a.z, c1a.w * c1a.w);
        u2.u[2] = pack2(c1b.x * c1b.x, c1b.y * c1b.y);
        u2.u[3] = pack2(c1b.z * c1b.z, c1b.w * c1b.w);
#pragma unroll
        for (int nt = 0; nt < 5; nt++) {
            bf16x8 b = *(const bf16x8*)&Ct[(nt * 16 + l15) * 72 + 32 + k0q];
            acc[nt] = __builtin_amdgcn_mfma_f32_16x16x32_bf16(
                nt < 2 ? u2.v : ua.v, b, acc[nt], 0, 0, 0);
        }

        c0a = n0a; c0b = n0b; c1a = n1a; c1b = n1b;
    }

    if (!valid) return;   // no barriers below

    // Epilogue (per wave). acc[nt][reg]: packed col = nt*16+l15, row = quad*4+reg.
    const int rbase = wavebase + quad * 4;
    const bool c2ok = (l15 < 14);
    const float d0 = Dvec[l15];
    const float d1 = c2ok ? Dvec[16 + l15] : 0.f;
    float llacc = 0.f;
#pragma unroll
    for (int r = 0; r < 4; r++) {
        const int row = rbase + r;
        float w0 = W[(size_t)row * 30 + l15];
        float w1 = c2ok ? W[(size_t)row * 30 + 16 + l15] : -1e30f;
        float m = fmaxf(w0, w1);
#pragma unroll
        for (int mm = 1; mm < 16; mm <<= 1) m = fmaxf(m, __shfl_xor(m, mm, 64));
        float e0 = __expf(w0 - m);
        float e1 = c2ok ? __expf(w1 - m) : 0.f;
        float s = e0 + e1;
#pragma unroll
        for (int mm = 1; mm < 16; mm <<= 1) s += __shfl_xor(s, mm, 64);
        float inv = 1.0f / s;
        float p0 = e0 * inv, p1 = e1 * inv;
        float Sn = S[row], Sn2 = Sn * Sn;
        float F0 = -0.5f * (acc[0][r] - 2.0f * Sn * acc[2][r] + Sn2 * d0);
        float F1 = -0.5f * (acc[1][r] - 2.0f * Sn * acc[3][r] + Sn2 * d1);
        float lp = p0 * F0 + (c2ok ? p1 * F1 : 0.f);
#pragma unroll
        for (int mm = 1; mm < 16; mm <<= 1) lp += __shfl_xor(lp, mm, 64);
        llacc += lp;

        out[2 + (size_t)row * 30 + l15] = p0;
        float lg0 = __logf(p0 + 1e-8f);
        Pb[(size_t)row * 32 + l15] = (unsigned short)f2bf_u(p0);
        Lb[(size_t)row * 32 + l15] = (unsigned short)f2bf_u(lg0);
        if (c2ok) {
            out[2 + (size_t)row * 30 + 16 + l15] = p1;
            float lg1 = __logf(p1 + 1e-8f);
            Pb[(size_t)row * 32 + 16 + l15] = (unsigned short)f2bf_u(p1);
            Lb[(size_t)row * 32 + 16 + l15] = (unsigned short)f2bf_u(lg1);
        } else {
            Pb[(size_t)row * 32 + 16 + l15] = 0;
            Lb[(size_t)row * 32 + 16 + l15] = 0;
        }
        if (l15 >= 14)                xl[(size_t)row * 8 + (l15 - 14)] = acc[3][r] + bl[l15 - 14];
        else if (l15 < 6)             xl[(size_t)row * 8 + (l15 + 2)]  = acc[4][r] + bl[l15 + 2];
        if (l15 >= 6 && l15 < 14)     xr[(size_t)row * 8 + (l15 - 6)]  = acc[4][r] + br[l15 - 6];
    }
    llacc += __shfl_xor(llacc, 16, 64);
    llacc += __shfl_xor(llacc, 32, 64);
    if (l == 0) atomicAdd(&out[0], llacc * (1.0f / N_CELLS));
}

// ---------------------------------------------------------------------------
// K2: edge pass A — p=exp(e) (no max-subtraction: |e| ~ O(10)); bf16 evals;
// denom atomics into 4 replicas (blockIdx&3) to cut line contention.
// ---------------------------------------------------------------------------
__global__ void edge_passA(const int* __restrict__ ei, const float* __restrict__ xl,
                           const float* __restrict__ xr, const float* __restrict__ att,
                           unsigned short* __restrict__ evalsB, float* __restrict__ denom4) {
    int e = blockIdx.x * 256 + threadIdx.x;
    if (e >= E_EDGES) return;
    int src = ei[e];
    int dst = ei[E_EDGES + e];
    const float4* lp = (const float4*)&xl[(size_t)src * 8];
    const float4* rp = (const float4*)&xr[(size_t)dst * 8];
    float4 l0 = lp[0], l1 = lp[1];
    float4 r0 = rp[0], r1 = rp[1];
    float ev = 0.f;
    ev += lrelu02(l0.x + r0.x) * att[0];
    ev += lrelu02(l0.y + r0.y) * att[1];
    ev += lrelu02(l0.z + r0.z) * att[2];
    ev += lrelu02(l0.w + r0.w) * att[3];
    ev += lrelu02(l1.x + r1.x) * att[4];
    ev += lrelu02(l1.y + r1.y) * att[5];
    ev += lrelu02(l1.z + r1.z) * att[6];
    ev += lrelu02(l1.w + r1.w) * att[7];
    float p = __expf(ev);
    evalsB[e] = (unsigned short)f2bf_u(p);
    atomicAdd(&denom4[(blockIdx.x & (NREP - 1)) * N_CELLS + dst], bf2f(f2bf_u(p)));
}

// ---------------------------------------------------------------------------
// K2b: fold denom replicas
// ---------------------------------------------------------------------------
__global__ void reduce_denom(const float* __restrict__ denom4, float* __restrict__ denom) {
    int i = blockIdx.x * 256 + threadIdx.x;
    if (i < N_CELLS)
        denom[i] = (denom4[i] + denom4[N_CELLS + i]) +
                   (denom4[2 * N_CELLS + i] + denom4[3 * N_CELLS + i]);
}

// ---------------------------------------------------------------------------
// K3: edge pass B — 1 thread/edge, bf16 64-B rows (2 cache lines/edge)
// ---------------------------------------------------------------------------
__global__ __launch_bounds__(256) void edge_passB(
    const int* __restrict__ ei, const unsigned short* __restrict__ evalsB,
    const float* __restrict__ denom, const unsigned short* __restrict__ Pb,
    const unsigned short* __restrict__ Lb, float* __restrict__ out) {
    const int t = threadIdx.x;
    const int e = blockIdx.x * 256 + t;     // E = 3125*256 exactly
    int src = ei[e];
    int dst = ei[E_EDGES + e];
    float alpha = bf2f(evalsB[e]) / (denom[dst] + 1e-16f);
    const int4* ps = (const int4*)&Pb[(size_t)src * 32];
    const int4* ld = (const int4*)&Lb[(size_t)dst * 32];
    int4 a0 = ps[0], a1 = ps[1], a2 = ps[2], a3 = ps[3];
    int4 b0 = ld[0], b1 = ld[1], b2 = ld[2], b3 = ld[3];
    float dot = dp4(a0, b0) + dp4(a1, b1) + dp4(a2, b2) + dp4(a3, b3);
    float contrib = -alpha * dot;

    for (int m = 1; m < 64; m <<= 1) contrib += __shfl_xor(contrib, m, 64);
    __shared__ float wsum[4];
    if ((t & 63) == 0) wsum[t >> 6] = contrib;
    __syncthreads();
    if (t == 0)
        atomicAdd(&out[1], (wsum[0] + wsum[1] + wsum[2] + wsum[3]) * (1.0f / N_CELLS));
}

// ---------------------------------------------------------------------------
// launch
// ---------------------------------------------------------------------------
extern "C" void kernel_launch(void* const* d_in, const int* in_sizes, int n_in,
                              void* d_out, int out_size, void* d_ws, size_t ws_size,
                              hipStream_t stream) {
    const float* X   = (const float*)d_in[0];
    const float* Mu  = (const float*)d_in[1];
    const float* Var = (const float*)d_in[2];
    const int*   ei  = (const int*)d_in[3];
    const float* W   = (const float*)d_in[4];
    const float* S   = (const float*)d_in[5];
    const float* Wl  = (const float*)d_in[6];
    const float* bl  = (const float*)d_in[7];
    const float* Wr  = (const float*)d_in[8];
    const float* br  = (const float*)d_in[9];
    const float* att = (const float*)d_in[10];

    float* out = (float*)d_out;

    // ws layout (float offsets), total 3,090,992 fl = 12.36 MB
    float* wsf = (float*)d_ws;
    unsigned short* CoefB  = (unsigned short*)wsf;             // [0, 40960)
    float* Dvec            = wsf + 40960;                      // 32
    unsigned short* Pb     = (unsigned short*)(wsf + 40992);   // N*32 us = 800000 fl
    unsigned short* Lb     = (unsigned short*)(wsf + 840992);  // N*32 us
    float* xl              = wsf + 1640992;                    // N*8
    float* xr              = wsf + 2040992;                    // N*8
    unsigned short* evalsB = (unsigned short*)(wsf + 2440992); // E us = 400000 fl
    float* denom           = wsf + 2840992;                    // N
    float* denom4          = wsf + 2890992;                    // 4*N

    prep_kernel<<<80, 256, 0, stream>>>(Mu, Var, Wl, Wr, CoefB, Dvec, denom4, out);
    main_rows_kernel<<<(N_CELLS + 63) / 64, 256, 0, stream>>>(
        X, W, S, bl, br, CoefB, Dvec, out, Pb, Lb, xl, xr);
    edge_passA<<<(E_EDGES + 255) / 256, 256, 0, stream>>>(ei, xl, xr, att, evalsB, denom4);
    reduce_denom<<<(N_CELLS + 255) / 256, 256, 0, stream>>>(denom4, denom);
    edge_passB<<<E_EDGES / 256, 256, 0, stream>>>(ei, evalsB, denom, Pb, Lb, out);
}